// Round 12
// baseline (59.423 us; speedup 1.0000x reference)
//
#include <hip/hip_runtime.h>
#include <hip/hip_bf16.h>

// KAN conv: out[b,o,h,w] = sum_{j,k,l,m} phi(x[b,j,h+k,w+l])[m] * coeff[o,j,k,l,m]
// phi = uniform cubic B-spline basis (8 bases, knots = linspace(0,1,12)).
// R12 = R11 chassis (K-split waves, wave-private barrier-free phi, depth-2
// A-prefetch ring, 32x32x16 MFMA) with O-SPLIT grid (blockIdx.z = o-half):
// wave tile 32o x 64w -> acc 32 AGPR (was 64). Register box shrinks 128->~90
// -> 5 waves/SIMD (20/CU, +25% TLP) against the measured latency wall.
// bt layout already supports o-half via +1024 B offset; A-traffic unchanged.

typedef short v8s __attribute__((ext_vector_type(8)));
typedef float v4f __attribute__((ext_vector_type(4)));
typedef float v16f __attribute__((ext_vector_type(16)));
typedef unsigned long long u64;
typedef u64 v2u64 __attribute__((ext_vector_type(2)));

#define B_N   16
#define CIN   64
#define COUT  64
#define H_IN  64
#define W_IN  64
#define NB    8
#define HO    62
#define WO    62
#define JC    8
#define NCH   8

__device__ __forceinline__ ushort f2bf(float f) {
    uint xu = __float_as_uint(f);
    return (ushort)((xu + 0x7fffu + ((xu >> 16) & 1u)) >> 16);
}

__device__ __forceinline__ uint cvtpk(float a, float b) {
    uint r;
    asm("v_cvt_pk_bf16_f32 %0, %1, %2" : "=v"(r) : "v"(a), "v"(b));
    return r;
}

// bt layout: [jc(8)][tap(9)][jp(4)][o(64)][g2(2)][m(8)] bf16, 576 KB.
__global__ void prep_coeff_kernel(const float* __restrict__ coeff, ushort* __restrict__ bt) {
    int n = blockIdx.x * 256 + threadIdx.x;
    if (n >= 294912) return;
    int m  = n & 7;
    int g2 = (n >> 3) & 1;
    int o  = (n >> 4) & 63;
    int jp = (n >> 10) & 3;
    int q  = n >> 12;
    int tap = q % 9;
    int jc  = q / 9;
    int j = jc * 8 + jp * 2 + g2;
    bt[n] = f2bf(coeff[((o * CIN + j) * 9 + tap) * 8 + m]);
}

#define MFMA32(a, b, c) __builtin_amdgcn_mfma_f32_32x32x16_bf16((a), (b), (c), 0, 0, 0)
#define MFMA16(a, b, c) __builtin_amdgcn_mfma_f32_16x16x32_bf16((a), (b), (c), 0, 0, 0)

__global__ __launch_bounds__(256, 5) void kan_conv_os(
        const float* __restrict__ x, const ushort* __restrict__ cb,
        float* __restrict__ out) {
    const int h    = blockIdx.x;      // 0..61
    const int b    = blockIdx.y;
    const int obh  = blockIdx.z;      // o-half 0/1
    const int tid  = threadIdx.x;
    const int lane = tid & 63;
    const int kh   = tid >> 6;        // wave id = K-split (jp = kh)
    const int l31  = lane & 31;
    const int g2   = lane >> 5;

    // 24 KB: phi (4 wave-private 6 KB regions [k(3)][j2(2)][w(64)][m(8)]) + reduce overlay
    __shared__ __align__(16) char smraw[24576];

    char* wrB = smraw + kh * 6144 + lane * 16;                   // + e*1024
    const char* rdB = smraw + kh * 6144 + g2 * 1024 + l31 * 16;  // + k*2048 + wf*512 + lt*16

    v16f c0 = (v16f)(0.f), c1 = (v16f)(0.f);   // w-low / w-high tiles (32o x 32w)

    float xr[6];
    const float* xb = x + ((size_t)(b * CIN) * H_IN + h) * W_IN + lane;
    const int jx = kh * 2;

// elem e = k*2 + j2 : x[b, jc*8 + jx + j2, h+k, w=lane]
#define XL(dst, jcn) { \
    _Pragma("unroll") \
    for (int e = 0; e < 6; ++e) \
        dst[e] = xb[(size_t)((jcn) * 8 + jx + (e & 1)) * (H_IN * W_IN) + (e >> 1) * W_IN]; \
    }

    auto PW = [&](float xval, int e) {   // lean phi-eval + single b128 write
        float s_ = fminf(fmaxf(xval * 11.0f, 0.0f), 10.999f);
        int i0 = (int)s_;
        float u  = s_ - (float)i0;
        float t  = 1.0f - u;
        float u2 = u * u, u3 = u2 * u;
        float t3 = t * t * t;
        const float inv6 = 1.0f / 6.0f;
        float n0 = t3 * inv6;
        float n3 = u3 * inv6;
        float n1 = fmaf(u2, fmaf(u, 0.5f, -1.0f), 2.0f / 3.0f);
        float n2 = 1.0f - n0 - n1 - n3;     // partition of unity
        u64 V = (u64)cvtpk(n0, n1) | ((u64)cvtpk(n2, n3) << 32);
        int bi = i0 - 3;   // first active basis index, in [-3, 7]
        u64 lo = bi < 0 ? (V >> (uint)(-16 * bi))
               : bi < 4 ? (V << (uint)(16 * bi)) : 0ull;
        u64 hi = bi <= 0 ? 0ull
               : bi < 4 ? (V >> (uint)(64 - 16 * bi))
               : (V << (uint)(16 * bi - 64));
        v2u64 pk; pk[0] = lo; pk[1] = hi;
        *reinterpret_cast<v2u64*>(wrB + e * 1024) = pk;
    };

    // A base for this wave's (kh, o-half, lane): o = obh*32 + l31
    const char* pA = (const char*)cb + (size_t)(kh * 128 + obh * 64 + l31 * 2 + g2) * 16;

    // A-frag 3-set ring (1 v8s per set): tap t consumes set t%3; load t+2 at t.
    v8s aA, aB, aC;

// consume C, issue load for tap t+2 into N, 2 B-reads (imm), 2 MFMAs
#define TAPR(k, lt, C, N, nptr) { \
    v8s b0 = *reinterpret_cast<const v8s*>(rdB + (k) * 2048 + (lt) * 16); \
    v8s b1 = *reinterpret_cast<const v8s*>(rdB + (k) * 2048 + 512 + (lt) * 16); \
    N = *reinterpret_cast<const v8s*>(nptr); \
    c0 = MFMA32(C, b0, c0); \
    c1 = MFMA32(C, b1, c1); }

// Chunk jc: GEMM(jc) with rotating A-prefetch || xload(jc+1) || phi-write(jc+1)
#define CHUNKP(jc) { \
    const char* pAc = pA + (size_t)(jc) * 73728; \
    const char* pAn = pA + (size_t)(((jc) + 1 < NCH) ? (jc) + 1 : 0) * 73728; \
    if ((jc) + 1 < NCH) XL(xr, (jc) + 1); \
    TAPR(0, 0, aA, aC, pAc + 2 * 8192); \
    TAPR(0, 1, aB, aA, pAc + 3 * 8192); \
    TAPR(0, 2, aC, aB, pAc + 4 * 8192); \
    if ((jc) + 1 < NCH) { PW(xr[0], 0); PW(xr[1], 1); } \
    TAPR(1, 0, aA, aC, pAc + 5 * 8192); \
    TAPR(1, 1, aB, aA, pAc + 6 * 8192); \
    TAPR(1, 2, aC, aB, pAc + 7 * 8192); \
    if ((jc) + 1 < NCH) { PW(xr[2], 2); PW(xr[3], 3); } \
    TAPR(2, 0, aA, aC, pAc + 8 * 8192); \
    TAPR(2, 1, aB, aA, pAn + 0 * 8192); \
    TAPR(2, 2, aC, aB, pAn + 1 * 8192); \
    if ((jc) + 1 < NCH) { PW(xr[4], 4); PW(xr[5], 5); } \
    }

    // prologue: phi(c0) (wave-private, in-order DS => no barrier) + A taps 0,1
    XL(xr, 0);
    aA = *reinterpret_cast<const v8s*>(pA);
    aB = *reinterpret_cast<const v8s*>(pA + 8192);
    PW(xr[0], 0); PW(xr[1], 1); PW(xr[2], 2);
    PW(xr[3], 3); PW(xr[4], 4); PW(xr[5], 5);

    CHUNKP(0); CHUNKP(1); CHUNKP(2); CHUNKP(3);
    CHUNKP(4); CHUNKP(5); CHUNKP(6); CHUNKP(7);

    // ---- epilogue: cross-wave K-reduce (<=8 KB arenas inside phi area) ----
#define WR1(C, off) { \
    _Pragma("unroll") \
    for (int q = 0; q < 4; ++q) { \
        v4f v; \
        _Pragma("unroll") \
        for (int z = 0; z < 4; ++z) v[z] = C[q * 4 + z]; \
        *reinterpret_cast<v4f*>(smraw + (off) + q * 1024 + lane * 16) = v; \
    } }
#define ADD1(C, off) { \
    _Pragma("unroll") \
    for (int q = 0; q < 4; ++q) { \
        v4f v = *reinterpret_cast<const v4f*>(smraw + (off) + q * 1024 + lane * 16); \
        _Pragma("unroll") \
        for (int z = 0; z < 4; ++z) C[q * 4 + z] += v[z]; \
    } }
#define STORE1(C, WF) { \
    int w = (WF) * 32 + l31; \
    if (w < WO) { \
        _Pragma("unroll") \
        for (int reg = 0; reg < 16; ++reg) { \
            int o = obh * 32 + (reg & 3) + 8 * (reg >> 2) + 4 * g2; \
            out[((b * COUT + o) * HO + h) * WO + w] = C[reg]; \
        } } }

    __syncthreads();                       // all GEMM reads of phi done
    if (kh == 1) { WR1(c0, 0);     WR1(c1, 4096); }
    if (kh == 3) { WR1(c0, 8192);  WR1(c1, 12288); }
    __syncthreads();
    if (kh == 0) { ADD1(c0, 0);    ADD1(c1, 4096); }    // j 0..3 sums
    if (kh == 2) { ADD1(c0, 8192); ADD1(c1, 12288); }   // j 4..7 sums
    __syncthreads();
    if (kh == 2) WR1(c0, 16384);           // w-low  (j4..7) -> kh0
    if (kh == 0) WR1(c1, 20480);           // w-high (j0..3) -> kh2
    __syncthreads();
    if (kh == 0) { ADD1(c0, 16384); STORE1(c0, 0); }    // w 0..31
    if (kh == 2) { ADD1(c1, 20480); STORE1(c1, 1); }    // w 32..63
}

// ---- fallback (ws too small for bt): R2-proven kernel, coeff from f32 ----
__global__ __launch_bounds__(256, 4) void kan_conv_fb(
        const float* __restrict__ x, const float* __restrict__ coeff_f,
        float* __restrict__ out) {
    const int h    = blockIdx.x;
    const int b    = blockIdx.y;
    const int tid  = threadIdx.x;
    const int lane = tid & 63;
    const int wv   = tid >> 6;
    const int g    = lane >> 4;
    const int l15  = lane & 15;
    const int obase = (wv >> 1) << 5;
    const int wbase = (wv & 1) << 5;

    __shared__ __align__(16) ushort phi_lds[3 * JC * W_IN * NB];
    __shared__ uint lut[72];
    if (tid < 72) {
        int tap = tid;
        int j  = tap / 9;
        int r9 = tap - j * 9;
        int kt = r9 / 3;
        int lt = r9 - kt * 3;
        lut[tap] = (uint)(((kt * JC + j) * W_IN) * NB) | ((uint)lt << 16)
                 | ((uint)j << 20) | ((uint)r9 << 24);
    }
    v4f acc00 = {0.f, 0.f, 0.f, 0.f};
    v4f acc01 = acc00, acc10 = acc00, acc11 = acc00;
    const int aoff = obase + l15;
    float xv[6];
    #pragma unroll
    for (int it = 0; it < 6; ++it) {
        int n = it * 256 + tid;
        xv[it] = x[((b * CIN + ((n >> 6) & 7)) * H_IN + (h + (n >> 9))) * W_IN + (n & 63)];
    }
    for (int jc = 0; jc < NCH; ++jc) {
        #pragma unroll
        for (int it = 0; it < 6; ++it) {
            int n = it * 256 + tid;
            float s  = xv[it] * 11.0f;
            int i0 = (int)s;
            i0 = i0 < 0 ? 0 : (i0 > 10 ? 10 : i0);
            float u  = s - (float)i0;
            float um = 1.0f - u;
            float u2 = u * u, u3 = u2 * u;
            const float inv6 = 1.0f / 6.0f;
            float n0 = um * um * um * inv6;
            float n1 = (3.0f * u3 - 6.0f * u2 + 4.0f) * inv6;
            float n2 = (-3.0f * u3 + 3.0f * u2 + 3.0f * u + 1.0f) * inv6;
            float n3 = u3 * inv6;
            u64 V = (u64)f2bf(n0) | ((u64)f2bf(n1) << 16)
                  | ((u64)f2bf(n2) << 32) | ((u64)f2bf(n3) << 48);
            int bi = i0 - 3;
            u64 lo = bi < 0 ? (V >> (uint)(-16 * bi))
                   : bi < 4 ? (V << (uint)(16 * bi)) : 0ull;
            u64 hi = bi <= 0 ? 0ull
                   : bi < 4 ? (V >> (uint)(64 - 16 * bi))
                   : (V << (uint)(16 * bi - 64));
            v2u64 pk; pk[0] = lo; pk[1] = hi;
            *reinterpret_cast<v2u64*>(&phi_lds[n << 3]) = pk;
        }
        if (jc + 1 < NCH) {
            int j0n = (jc + 1) * JC;
            #pragma unroll
            for (int it = 0; it < 6; ++it) {
                int n = it * 256 + tid;
                xv[it] = x[((b * CIN + j0n + ((n >> 6) & 7)) * H_IN + (h + (n >> 9))) * W_IN + (n & 63)];
            }
        }
        __syncthreads();
        const int j0 = jc * JC;
        #pragma unroll 6
        for (int kk = 0; kk < 18; ++kk) {
            int tap = (kk << 2) + g;
            uint e = lut[tap];
            int philoc = (int)(e & 0xffffu);
            int lt     = (int)((e >> 16) & 3u);
            int w0 = wbase + l15 + lt;
            int w1 = w0 + 16;
            w0 = w0 < 63 ? w0 : 63;
            w1 = w1 < 63 ? w1 : 63;
            v8s pb0 = *reinterpret_cast<const v8s*>(&phi_lds[philoc + (w0 << 3)]);
            v8s pb1 = *reinterpret_cast<const v8s*>(&phi_lds[philoc + (w1 << 3)]);
            int j  = (int)((e >> 20) & 15u);
            int r9 = (int)((e >> 24) & 15u);
            const float* cf = coeff_f + (((aoff * CIN + (j0 + j)) * 9 + r9) << 3);
            v8s pa0, pa1;
            #pragma unroll
            for (int z = 0; z < 8; ++z) pa0[z] = (short)f2bf(cf[z]);
            const float* cf2 = cf + (CIN * 9 * NB * 16);
            #pragma unroll
            for (int z = 0; z < 8; ++z) pa1[z] = (short)f2bf(cf2[z]);
            acc00 = MFMA16(pa0, pb0, acc00);
            acc01 = MFMA16(pa0, pb1, acc01);
            acc10 = MFMA16(pa1, pb0, acc10);
            acc11 = MFMA16(pa1, pb1, acc11);
        }
        __syncthreads();
    }
    const int wc0 = wbase + l15;
    const int wc1 = wc0 + 16;
    #pragma unroll
    for (int i = 0; i < 2; ++i) {
        v4f a0 = (i == 0) ? acc00 : acc10;
        v4f a1 = (i == 0) ? acc01 : acc11;
        int o = obase + i * 16 + (g << 2);
        #pragma unroll
        for (int r = 0; r < 4; ++r) {
            int off = ((b * COUT + o + r) * HO + h) * WO;
            if (wc0 < WO) out[off + wc0] = a0[r];
            if (wc1 < WO) out[off + wc1] = a1[r];
        }
    }
}

extern "C" void kernel_launch(void* const* d_in, const int* in_sizes, int n_in,
                              void* d_out, int out_size, void* d_ws, size_t ws_size,
                              hipStream_t stream) {
    const float* x     = (const float*)d_in[0];
    const float* coeff = (const float*)d_in[1];
    float* out = (float*)d_out;

    const size_t bt_bytes = (size_t)294912 * 2;  // 576 KB
    if (ws_size >= bt_bytes) {
        ushort* bt = (ushort*)d_ws;
        prep_coeff_kernel<<<(294912 + 255) / 256, 256, 0, stream>>>(coeff, bt);
        kan_conv_os<<<dim3(HO, B_N, 2), 256, 0, stream>>>(x, bt, out);
    } else {
        kan_conv_fb<<<dim3(HO, B_N), 256, 0, stream>>>(x, coeff, out);
    }
}

// Round 13
// 54.427 us; speedup vs baseline: 1.0918x; 1.0918x over previous
//
#include <hip/hip_runtime.h>
#include <hip/hip_bf16.h>

// KAN conv: out[b,o,h,w] = sum_{j,k,l,m} phi(x[b,j,h+k,w+l])[m] * coeff[o,j,k,l,m]
// phi = uniform cubic B-spline basis (8 bases, knots = linspace(0,1,12)).
// R13: 512-thread block (8 waves = 4 kh K-split x 2 oh o-half) per (b,h).
// Wave tile 32o x 64w -> acc 32, freeing regs for BOTH A depth-2 ring and
// B (LDS) depth-1 ring. phi shared between oh-twins (each stages 3/6 elems ->
// per-CU phi-VALU = R11, no R12 duplication), double-buffered, 1 barrier/chunk.

typedef short v8s __attribute__((ext_vector_type(8)));
typedef float v4f __attribute__((ext_vector_type(4)));
typedef float v16f __attribute__((ext_vector_type(16)));
typedef unsigned long long u64;
typedef u64 v2u64 __attribute__((ext_vector_type(2)));

#define B_N   16
#define CIN   64
#define COUT  64
#define H_IN  64
#define W_IN  64
#define NB    8
#define HO    62
#define WO    62
#define JC    8
#define NCH   8

__device__ __forceinline__ ushort f2bf(float f) {
    uint xu = __float_as_uint(f);
    return (ushort)((xu + 0x7fffu + ((xu >> 16) & 1u)) >> 16);
}

__device__ __forceinline__ uint cvtpk(float a, float b) {
    uint r;
    asm("v_cvt_pk_bf16_f32 %0, %1, %2" : "=v"(r) : "v"(a), "v"(b));
    return r;
}

// bt layout: [jc(8)][tap(9)][jp(4)][o(64)][g2(2)][m(8)] bf16, 576 KB.
__global__ void prep_coeff_kernel(const float* __restrict__ coeff, ushort* __restrict__ bt) {
    int n = blockIdx.x * 256 + threadIdx.x;
    if (n >= 294912) return;
    int m  = n & 7;
    int g2 = (n >> 3) & 1;
    int o  = (n >> 4) & 63;
    int jp = (n >> 10) & 3;
    int q  = n >> 12;
    int tap = q % 9;
    int jc  = q / 9;
    int j = jc * 8 + jp * 2 + g2;
    bt[n] = f2bf(coeff[((o * CIN + j) * 9 + tap) * 8 + m]);
}

#define MFMA32(a, b, c) __builtin_amdgcn_mfma_f32_32x32x16_bf16((a), (b), (c), 0, 0, 0)
#define MFMA16(a, b, c) __builtin_amdgcn_mfma_f32_16x16x32_bf16((a), (b), (c), 0, 0, 0)

__global__ __launch_bounds__(512, 4) void kan_conv_dr(
        const float* __restrict__ x, const ushort* __restrict__ cb,
        float* __restrict__ out) {
    const int h    = blockIdx.x;      // 0..61
    const int b    = blockIdx.y;
    const int tid  = threadIdx.x;
    const int lane = tid & 63;
    const int wv   = tid >> 6;        // 0..7
    const int kh   = wv & 3;          // K-split (j-pair)
    const int oh   = wv >> 2;         // o-half
    const int l31  = lane & 31;
    const int g2   = lane >> 5;

    // phi dbuf: 2 x [kh(4)][k(3)][j2(2)][w(64)][m(8)] = 2 x 24 KB (+pad for
    // clamped-col overreads); reduce overlays first 32 KB after final barrier.
    __shared__ __align__(16) char smraw[49408];

    char* const wrBb = smraw + kh * 6144 + lane * 16;                   // + buf*24576 + e*1024
    const char* const rdBb = smraw + kh * 6144 + g2 * 1024 + l31 * 16;  // + buf*24576 + k*2048 + wf*512 + lt*16

    v16f c0 = (v16f)(0.f), c1 = (v16f)(0.f);   // w-low / w-high (32o x 32w each)

    float xr[3];
    const int jx  = kh * 2;
    const int eo0 = oh * 3;           // this wave's first staging elem
    const float* xb = x + ((size_t)(b * CIN) * H_IN + h) * W_IN + lane;

// stage-loads for this wave's 3 elems of chunk jcn (e = eo0..eo0+2, e=k*2+j2)
#define XL3(jcn) { \
    _Pragma("unroll") \
    for (int i = 0; i < 3; ++i) { \
        int e_ = eo0 + i; \
        xr[i] = xb[(size_t)((jcn) * 8 + jx + (e_ & 1)) * (H_IN * W_IN) + (e_ >> 1) * W_IN]; \
    } }

    auto PW = [&](float xval, int e, char* wb) {   // lean phi-eval + b128 write
        float s_ = fminf(fmaxf(xval * 11.0f, 0.0f), 10.999f);
        int i0 = (int)s_;
        float u  = s_ - (float)i0;
        float t  = 1.0f - u;
        float u2 = u * u, u3 = u2 * u;
        float t3 = t * t * t;
        const float inv6 = 1.0f / 6.0f;
        float n0 = t3 * inv6;
        float n3 = u3 * inv6;
        float n1 = fmaf(u2, fmaf(u, 0.5f, -1.0f), 2.0f / 3.0f);
        float n2 = 1.0f - n0 - n1 - n3;     // partition of unity
        u64 V = (u64)cvtpk(n0, n1) | ((u64)cvtpk(n2, n3) << 32);
        int bi = i0 - 3;   // first active basis index, in [-3, 7]
        u64 lo = bi < 0 ? (V >> (uint)(-16 * bi))
               : bi < 4 ? (V << (uint)(16 * bi)) : 0ull;
        u64 hi = bi <= 0 ? 0ull
               : bi < 4 ? (V >> (uint)(64 - 16 * bi))
               : (V << (uint)(16 * bi - 64));
        v2u64 pk; pk[0] = lo; pk[1] = hi;
        *reinterpret_cast<v2u64*>(wb + e * 1024) = pk;
    };

    // A base: o = oh*32 + l31 -> (kh*128 + oh*64 + l31*2 + g2)*16 bytes
    const char* pA = (const char*)cb + (size_t)(kh * 128 + oh * 64 + l31 * 2 + g2) * 16;

    v8s aA, aB, aC;                // A ring (depth-2, 3 sets)
    v8s bE0, bE1, bO0, bO1;        // B ring (depth-1, even/odd sets)

// Chunk jc: read buf jc&1, stage (jc+1) into buf (jc+1)&1; 1 barrier at end.
// Taps t=0..8: consume A set t%3 (load t+2), consume B set t&1 (read t+1).
#define CHUNKX(jc) { \
    const char* pAc = pA + (size_t)(jc) * 73728; \
    const char* pAn = pA + (size_t)(((jc) + 1) & 7) * 73728; \
    const char* rb  = rdBb + ((jc) & 1) * 24576; \
    char* wb        = wrBb + (((jc) + 1) & 1) * 24576; \
    bE0 = *(const v8s*)(rb);                  bE1 = *(const v8s*)(rb + 512); \
    if ((jc) + 1 < NCH) XL3((jc) + 1); \
    /*t0 k0l0*/ aC = *(const v8s*)(pAc + 16384); \
        bO0 = *(const v8s*)(rb + 16);         bO1 = *(const v8s*)(rb + 528); \
        c0 = MFMA32(aA, bE0, c0);             c1 = MFMA32(aA, bE1, c1); \
    /*t1 k0l1*/ aA = *(const v8s*)(pAc + 24576); \
        bE0 = *(const v8s*)(rb + 32);         bE1 = *(const v8s*)(rb + 544); \
        c0 = MFMA32(aB, bO0, c0);             c1 = MFMA32(aB, bO1, c1); \
    /*t2 k0l2*/ aB = *(const v8s*)(pAc + 32768); \
        bO0 = *(const v8s*)(rb + 2048);       bO1 = *(const v8s*)(rb + 2560); \
        c0 = MFMA32(aC, bE0, c0);             c1 = MFMA32(aC, bE1, c1); \
    /*t3 k1l0*/ aC = *(const v8s*)(pAc + 40960); \
        bE0 = *(const v8s*)(rb + 2064);       bE1 = *(const v8s*)(rb + 2576); \
        c0 = MFMA32(aA, bO0, c0);             c1 = MFMA32(aA, bO1, c1); \
    /*t4 k1l1*/ aA = *(const v8s*)(pAc + 49152); \
        bO0 = *(const v8s*)(rb + 2080);       bO1 = *(const v8s*)(rb + 2592); \
        c0 = MFMA32(aB, bE0, c0);             c1 = MFMA32(aB, bE1, c1); \
    if ((jc) + 1 < NCH) PW(xr[0], eo0, wb); \
    /*t5 k1l2*/ aB = *(const v8s*)(pAc + 57344); \
        bE0 = *(const v8s*)(rb + 4096);       bE1 = *(const v8s*)(rb + 4608); \
        c0 = MFMA32(aC, bO0, c0);             c1 = MFMA32(aC, bO1, c1); \
    /*t6 k2l0*/ aC = *(const v8s*)(pAc + 65536); \
        bO0 = *(const v8s*)(rb + 4112);       bO1 = *(const v8s*)(rb + 4624); \
        c0 = MFMA32(aA, bE0, c0);             c1 = MFMA32(aA, bE1, c1); \
    if ((jc) + 1 < NCH) PW(xr[1], eo0 + 1, wb); \
    /*t7 k2l1*/ aA = *(const v8s*)(pAn); \
        bE0 = *(const v8s*)(rb + 4128);       bE1 = *(const v8s*)(rb + 4640); \
        c0 = MFMA32(aB, bO0, c0);             c1 = MFMA32(aB, bO1, c1); \
    /*t8 k2l2*/ aB = *(const v8s*)(pAn + 8192); \
        c0 = MFMA32(aC, bE0, c0);             c1 = MFMA32(aC, bE1, c1); \
    if ((jc) + 1 < NCH) PW(xr[2], eo0 + 2, wb); \
    __syncthreads(); \
    }

    // prologue: stage chunk 0 into buf0 (twins split elems), preload A t0,t1
    XL3(0);
    aA = *(const v8s*)(pA);
    aB = *(const v8s*)(pA + 8192);
    PW(xr[0], eo0, wrBb); PW(xr[1], eo0 + 1, wrBb); PW(xr[2], eo0 + 2, wrBb);
    __syncthreads();

    CHUNKX(0); CHUNKX(1); CHUNKX(2); CHUNKX(3);
    CHUNKX(4); CHUNKX(5); CHUNKX(6); CHUNKX(7);

    // ---- epilogue: per-oh kh-reduce (disjoint 16 KB arenas), static indices ----
#define WR1(C, off) { \
    _Pragma("unroll") \
    for (int q = 0; q < 4; ++q) { \
        v4f v; \
        _Pragma("unroll") \
        for (int z = 0; z < 4; ++z) v[z] = C[q * 4 + z]; \
        *reinterpret_cast<v4f*>(smraw + (off) + q * 1024 + lane * 16) = v; \
    } }
#define ADD1(C, off) { \
    _Pragma("unroll") \
    for (int q = 0; q < 4; ++q) { \
        v4f v = *reinterpret_cast<const v4f*>(smraw + (off) + q * 1024 + lane * 16); \
        _Pragma("unroll") \
        for (int z = 0; z < 4; ++z) C[q * 4 + z] += v[z]; \
    } }
#define STORE1(C, WF) { \
    int w = (WF) * 32 + l31; \
    if (w < WO) { \
        _Pragma("unroll") \
        for (int reg = 0; reg < 16; ++reg) { \
            int o = oh * 32 + (reg & 3) + 8 * (reg >> 2) + 4 * g2; \
            out[((b * COUT + o) * HO + h) * WO + w] = C[reg]; \
        } } }

    const int ro = oh * 16384;
    __syncthreads();                       // all GEMM reads of phi done
    if (kh == 1) { WR1(c0, ro);        WR1(c1, ro + 4096); }
    if (kh == 3) { WR1(c0, ro + 8192); WR1(c1, ro + 12288); }
    __syncthreads();
    if (kh == 0) { ADD1(c0, ro);        ADD1(c1, ro + 4096); }
    if (kh == 2) { ADD1(c0, ro + 8192); ADD1(c1, ro + 12288); }
    __syncthreads();
    if (kh == 2) WR1(c0, ro);              // w-low (j4..7)  -> kh0
    if (kh == 0) WR1(c1, ro + 4096);       // w-high (j0..3) -> kh2
    __syncthreads();
    if (kh == 0) { ADD1(c0, ro);        STORE1(c0, 0); }   // w 0..31
    if (kh == 2) { ADD1(c1, ro + 4096); STORE1(c1, 1); }   // w 32..63
}

// ---- fallback (ws too small for bt): R2-proven kernel, coeff from f32 ----
__global__ __launch_bounds__(256, 4) void kan_conv_fb(
        const float* __restrict__ x, const float* __restrict__ coeff_f,
        float* __restrict__ out) {
    const int h    = blockIdx.x;
    const int b    = blockIdx.y;
    const int tid  = threadIdx.x;
    const int lane = tid & 63;
    const int wv   = tid >> 6;
    const int g    = lane >> 4;
    const int l15  = lane & 15;
    const int obase = (wv >> 1) << 5;
    const int wbase = (wv & 1) << 5;

    __shared__ __align__(16) ushort phi_lds[3 * JC * W_IN * NB];
    __shared__ uint lut[72];
    if (tid < 72) {
        int tap = tid;
        int j  = tap / 9;
        int r9 = tap - j * 9;
        int kt = r9 / 3;
        int lt = r9 - kt * 3;
        lut[tap] = (uint)(((kt * JC + j) * W_IN) * NB) | ((uint)lt << 16)
                 | ((uint)j << 20) | ((uint)r9 << 24);
    }
    v4f acc00 = {0.f, 0.f, 0.f, 0.f};
    v4f acc01 = acc00, acc10 = acc00, acc11 = acc00;
    const int aoff = obase + l15;
    float xv[6];
    #pragma unroll
    for (int it = 0; it < 6; ++it) {
        int n = it * 256 + tid;
        xv[it] = x[((b * CIN + ((n >> 6) & 7)) * H_IN + (h + (n >> 9))) * W_IN + (n & 63)];
    }
    for (int jc = 0; jc < NCH; ++jc) {
        #pragma unroll
        for (int it = 0; it < 6; ++it) {
            int n = it * 256 + tid;
            float s  = xv[it] * 11.0f;
            int i0 = (int)s;
            i0 = i0 < 0 ? 0 : (i0 > 10 ? 10 : i0);
            float u  = s - (float)i0;
            float um = 1.0f - u;
            float u2 = u * u, u3 = u2 * u;
            const float inv6 = 1.0f / 6.0f;
            float n0 = um * um * um * inv6;
            float n1 = (3.0f * u3 - 6.0f * u2 + 4.0f) * inv6;
            float n2 = (-3.0f * u3 + 3.0f * u2 + 3.0f * u + 1.0f) * inv6;
            float n3 = u3 * inv6;
            u64 V = (u64)f2bf(n0) | ((u64)f2bf(n1) << 16)
                  | ((u64)f2bf(n2) << 32) | ((u64)f2bf(n3) << 48);
            int bi = i0 - 3;
            u64 lo = bi < 0 ? (V >> (uint)(-16 * bi))
                   : bi < 4 ? (V << (uint)(16 * bi)) : 0ull;
            u64 hi = bi <= 0 ? 0ull
                   : bi < 4 ? (V >> (uint)(64 - 16 * bi))
                   : (V << (uint)(16 * bi - 64));
            v2u64 pk; pk[0] = lo; pk[1] = hi;
            *reinterpret_cast<v2u64*>(&phi_lds[n << 3]) = pk;
        }
        if (jc + 1 < NCH) {
            int j0n = (jc + 1) * JC;
            #pragma unroll
            for (int it = 0; it < 6; ++it) {
                int n = it * 256 + tid;
                xv[it] = x[((b * CIN + j0n + ((n >> 6) & 7)) * H_IN + (h + (n >> 9))) * W_IN + (n & 63)];
            }
        }
        __syncthreads();
        const int j0 = jc * JC;
        #pragma unroll 6
        for (int kk = 0; kk < 18; ++kk) {
            int tap = (kk << 2) + g;
            uint e = lut[tap];
            int philoc = (int)(e & 0xffffu);
            int lt     = (int)((e >> 16) & 3u);
            int w0 = wbase + l15 + lt;
            int w1 = w0 + 16;
            w0 = w0 < 63 ? w0 : 63;
            w1 = w1 < 63 ? w1 : 63;
            v8s pb0 = *reinterpret_cast<const v8s*>(&phi_lds[philoc + (w0 << 3)]);
            v8s pb1 = *reinterpret_cast<const v8s*>(&phi_lds[philoc + (w1 << 3)]);
            int j  = (int)((e >> 20) & 15u);
            int r9 = (int)((e >> 24) & 15u);
            const float* cf = coeff_f + (((aoff * CIN + (j0 + j)) * 9 + r9) << 3);
            v8s pa0, pa1;
            #pragma unroll
            for (int z = 0; z < 8; ++z) pa0[z] = (short)f2bf(cf[z]);
            const float* cf2 = cf + (CIN * 9 * NB * 16);
            #pragma unroll
            for (int z = 0; z < 8; ++z) pa1[z] = (short)f2bf(cf2[z]);
            acc00 = MFMA16(pa0, pb0, acc00);
            acc01 = MFMA16(pa0, pb1, acc01);
            acc10 = MFMA16(pa1, pb0, acc10);
            acc11 = MFMA16(pa1, pb1, acc11);
        }
        __syncthreads();
    }
    const int wc0 = wbase + l15;
    const int wc1 = wc0 + 16;
    #pragma unroll
    for (int i = 0; i < 2; ++i) {
        v4f a0 = (i == 0) ? acc00 : acc10;
        v4f a1 = (i == 0) ? acc01 : acc11;
        int o = obase + i * 16 + (g << 2);
        #pragma unroll
        for (int r = 0; r < 4; ++r) {
            int off = ((b * COUT + o + r) * HO + h) * WO;
            if (wc0 < WO) out[off + wc0] = a0[r];
            if (wc1 < WO) out[off + wc1] = a1[r];
        }
    }
}

extern "C" void kernel_launch(void* const* d_in, const int* in_sizes, int n_in,
                              void* d_out, int out_size, void* d_ws, size_t ws_size,
                              hipStream_t stream) {
    const float* x     = (const float*)d_in[0];
    const float* coeff = (const float*)d_in[1];
    float* out = (float*)d_out;

    const size_t bt_bytes = (size_t)294912 * 2;  // 576 KB
    if (ws_size >= bt_bytes) {
        ushort* bt = (ushort*)d_ws;
        prep_coeff_kernel<<<(294912 + 255) / 256, 256, 0, stream>>>(coeff, bt);
        kan_conv_dr<<<dim3(HO, B_N), 512, 0, stream>>>(x, bt, out);
    } else {
        kan_conv_fb<<<dim3(HO, B_N), 256, 0, stream>>>(x, coeff, out);
    }
}

// Round 15
// 51.518 us; speedup vs baseline: 1.1534x; 1.0565x over previous
//
#include <hip/hip_runtime.h>
#include <hip/hip_bf16.h>

// KAN conv: out[b,o,h,w] = sum_{j,k,l,m} phi(x[b,j,h+k,w+l])[m] * coeff[o,j,k,l,m]
// phi = uniform cubic B-spline basis (8 bases, knots = linspace(0,1,12)).
// R15 = R11 (proven 47us: K-split waves, wave-private barrier-free phi staging,
// depth-2 A-prefetch register ring, 32x32x16 MFMA) + T1 XCD-aware block
// swizzle (992 blocks % 8 == 0 -> bijective; consecutive blocks on one XCD
// share x rows h+-1 and the bt stream -> L2 locality). R14's DMA+phi-table
// path abandoned: 13us table-write tax ~= conv saving, plus LDS race risk.

typedef short v8s __attribute__((ext_vector_type(8)));
typedef float v4f __attribute__((ext_vector_type(4)));
typedef float v16f __attribute__((ext_vector_type(16)));
typedef unsigned long long u64;
typedef u64 v2u64 __attribute__((ext_vector_type(2)));

#define B_N   16
#define CIN   64
#define COUT  64
#define H_IN  64
#define W_IN  64
#define NB    8
#define HO    62
#define WO    62
#define JC    8
#define NCH   8

__device__ __forceinline__ ushort f2bf(float f) {
    uint xu = __float_as_uint(f);
    return (ushort)((xu + 0x7fffu + ((xu >> 16) & 1u)) >> 16);
}

__device__ __forceinline__ uint cvtpk(float a, float b) {
    uint r;
    asm("v_cvt_pk_bf16_f32 %0, %1, %2" : "=v"(r) : "v"(a), "v"(b));
    return r;
}

// bt layout: [jc(8)][tap(9)][jp(4)][o(64)][g2(2)][m(8)] bf16, 576 KB.
__global__ void prep_coeff_kernel(const float* __restrict__ coeff, ushort* __restrict__ bt) {
    int n = blockIdx.x * 256 + threadIdx.x;
    if (n >= 294912) return;
    int m  = n & 7;
    int g2 = (n >> 3) & 1;
    int o  = (n >> 4) & 63;
    int jp = (n >> 10) & 3;
    int q  = n >> 12;
    int tap = q % 9;
    int jc  = q / 9;
    int j = jc * 8 + jp * 2 + g2;
    bt[n] = f2bf(coeff[((o * CIN + j) * 9 + tap) * 8 + m]);
}

#define MFMA32(a, b, c) __builtin_amdgcn_mfma_f32_32x32x16_bf16((a), (b), (c), 0, 0, 0)
#define MFMA16(a, b, c) __builtin_amdgcn_mfma_f32_16x16x32_bf16((a), (b), (c), 0, 0, 0)

__global__ __launch_bounds__(256, 4) void kan_conv_pf(
        const float* __restrict__ x, const ushort* __restrict__ cb,
        float* __restrict__ out) {
    // T1 XCD swizzle: XCD xc gets contiguous sids [xc*124, (xc+1)*124)
    const int bid = blockIdx.x;
    const int sid = (bid & 7) * 124 + (bid >> 3);
    const int b   = sid / 62;
    const int h   = sid - b * 62;

    const int tid  = threadIdx.x;
    const int lane = tid & 63;
    const int kh   = tid >> 6;        // wave id = K-split (jp = kh)
    const int l31  = lane & 31;
    const int g2   = lane >> 5;

    // 24 KB phi (4 wave-private 6 KB regions [k(3)][j2(2)][w(64)][m(8)]) + reduce
    __shared__ __align__(16) char smraw[32768];

    char* wrB = smraw + kh * 6144 + lane * 16;                   // + e*1024
    const char* rdB = smraw + kh * 6144 + g2 * 1024 + l31 * 16;  // + k*2048 + wf*512 + lt*16

    v16f acc[2][2];
    acc[0][0] = (v16f)(0.f); acc[0][1] = (v16f)(0.f);
    acc[1][0] = (v16f)(0.f); acc[1][1] = (v16f)(0.f);

    float xr[6];
    const float* xb = x + ((size_t)(b * CIN) * H_IN + h) * W_IN + lane;
    const int jx = kh * 2;

// elem e = k*2 + j2 : x[b, jc*8 + jx + j2, h+k, w=lane]
#define XL(dst, jcn) { \
    _Pragma("unroll") \
    for (int e = 0; e < 6; ++e) \
        dst[e] = xb[(size_t)((jcn) * 8 + jx + (e & 1)) * (H_IN * W_IN) + (e >> 1) * W_IN]; \
    }

    auto PW = [&](float xval, int e) {   // lean phi-eval + single b128 write
        float s_ = fminf(fmaxf(xval * 11.0f, 0.0f), 10.999f);
        int i0 = (int)s_;
        float u  = s_ - (float)i0;
        float t  = 1.0f - u;
        float u2 = u * u, u3 = u2 * u;
        float t3 = t * t * t;
        const float inv6 = 1.0f / 6.0f;
        float n0 = t3 * inv6;
        float n3 = u3 * inv6;
        float n1 = fmaf(u2, fmaf(u, 0.5f, -1.0f), 2.0f / 3.0f);
        float n2 = 1.0f - n0 - n1 - n3;     // partition of unity
        u64 V = (u64)cvtpk(n0, n1) | ((u64)cvtpk(n2, n3) << 32);
        int bi = i0 - 3;   // first active basis index, in [-3, 7]
        u64 lo = bi < 0 ? (V >> (uint)(-16 * bi))
               : bi < 4 ? (V << (uint)(16 * bi)) : 0ull;
        u64 hi = bi <= 0 ? 0ull
               : bi < 4 ? (V >> (uint)(64 - 16 * bi))
               : (V << (uint)(16 * bi - 64));
        v2u64 pk; pk[0] = lo; pk[1] = hi;
        *reinterpret_cast<v2u64*>(wrB + e * 1024) = pk;
    };

    const char* pA = (const char*)cb + (size_t)(kh * 128 + l31 * 2 + g2) * 16;

    // A-frag 3-set ring: tap t consumes set S(t%3); loads for t+2 issued at t.
    v8s a0A, a1A, a0B, a1B, a0C, a1C;

// consume (C0,C1), issue loads for tap t+2 into (N0,N1), then 4 MFMAs
#define TAPR(k, lt, C0, C1, N0, N1, nptr) { \
    v8s b0 = *reinterpret_cast<const v8s*>(rdB + (k) * 2048 + (lt) * 16); \
    v8s b1 = *reinterpret_cast<const v8s*>(rdB + (k) * 2048 + 512 + (lt) * 16); \
    N0 = *reinterpret_cast<const v8s*>(nptr); \
    N1 = *reinterpret_cast<const v8s*>((nptr) + 1024); \
    acc[0][0] = MFMA32(C0, b0, acc[0][0]); \
    acc[0][1] = MFMA32(C0, b1, acc[0][1]); \
    acc[1][0] = MFMA32(C1, b0, acc[1][0]); \
    acc[1][1] = MFMA32(C1, b1, acc[1][1]); }

// Chunk jc: GEMM(jc) with rotating A-prefetch || xload(jc+1) || phi-write(jc+1)
#define CHUNKP(jc) { \
    const char* pAc = pA + (size_t)(jc) * 73728; \
    const char* pAn = pA + (size_t)(((jc) + 1 < NCH) ? (jc) + 1 : 0) * 73728; \
    if ((jc) + 1 < NCH) XL(xr, (jc) + 1); \
    TAPR(0, 0, a0A, a1A, a0C, a1C, pAc + 2 * 8192); \
    TAPR(0, 1, a0B, a1B, a0A, a1A, pAc + 3 * 8192); \
    TAPR(0, 2, a0C, a1C, a0B, a1B, pAc + 4 * 8192); \
    if ((jc) + 1 < NCH) { PW(xr[0], 0); PW(xr[1], 1); } \
    TAPR(1, 0, a0A, a1A, a0C, a1C, pAc + 5 * 8192); \
    TAPR(1, 1, a0B, a1B, a0A, a1A, pAc + 6 * 8192); \
    TAPR(1, 2, a0C, a1C, a0B, a1B, pAc + 7 * 8192); \
    if ((jc) + 1 < NCH) { PW(xr[2], 2); PW(xr[3], 3); } \
    TAPR(2, 0, a0A, a1A, a0C, a1C, pAc + 8 * 8192); \
    TAPR(2, 1, a0B, a1B, a0A, a1A, pAn + 0 * 8192); \
    TAPR(2, 2, a0C, a1C, a0B, a1B, pAn + 1 * 8192); \
    if ((jc) + 1 < NCH) { PW(xr[4], 4); PW(xr[5], 5); } \
    }

    // prologue: phi(c0) (wave-private, in-order DS => no barrier) + A taps 0,1
    XL(xr, 0);
    PW(xr[0], 0); PW(xr[1], 1); PW(xr[2], 2);
    PW(xr[3], 3); PW(xr[4], 4); PW(xr[5], 5);
    a0A = *reinterpret_cast<const v8s*>(pA);
    a1A = *reinterpret_cast<const v8s*>(pA + 1024);
    a0B = *reinterpret_cast<const v8s*>(pA + 8192);
    a1B = *reinterpret_cast<const v8s*>(pA + 8192 + 1024);

    CHUNKP(0); CHUNKP(1); CHUNKP(2); CHUNKP(3);
    CHUNKP(4); CHUNKP(5); CHUNKP(6); CHUNKP(7);

    // ---- epilogue: parallel 2-round cross-wave K-reduce, ALL static indices ----
#define WR_FULL(off) { \
    _Pragma("unroll") \
    for (int t = 0; t < 4; ++t) { \
        _Pragma("unroll") \
        for (int q = 0; q < 4; ++q) { \
            v4f v; \
            _Pragma("unroll") \
            for (int z = 0; z < 4; ++z) v[z] = acc[t >> 1][t & 1][q * 4 + z]; \
            *reinterpret_cast<v4f*>(smraw + (off) + (t * 4 + q) * 1024 + lane * 16) = v; \
        } } }
#define ADD_FULL(off) { \
    _Pragma("unroll") \
    for (int t = 0; t < 4; ++t) { \
        _Pragma("unroll") \
        for (int q = 0; q < 4; ++q) { \
            v4f v = *reinterpret_cast<const v4f*>(smraw + (off) + (t * 4 + q) * 1024 + lane * 16); \
            _Pragma("unroll") \
            for (int z = 0; z < 4; ++z) acc[t >> 1][t & 1][q * 4 + z] += v[z]; \
        } } }
#define WR_HALF(OT, off) { \
    _Pragma("unroll") \
    for (int wf = 0; wf < 2; ++wf) { \
        _Pragma("unroll") \
        for (int q = 0; q < 4; ++q) { \
            v4f v; \
            _Pragma("unroll") \
            for (int z = 0; z < 4; ++z) v[z] = acc[OT][wf][q * 4 + z]; \
            *reinterpret_cast<v4f*>(smraw + (off) + (wf * 4 + q) * 1024 + lane * 16) = v; \
        } } }
#define ADD_HALF(OT, off) { \
    _Pragma("unroll") \
    for (int wf = 0; wf < 2; ++wf) { \
        _Pragma("unroll") \
        for (int q = 0; q < 4; ++q) { \
            v4f v = *reinterpret_cast<const v4f*>(smraw + (off) + (wf * 4 + q) * 1024 + lane * 16); \
            _Pragma("unroll") \
            for (int z = 0; z < 4; ++z) acc[OT][wf][q * 4 + z] += v[z]; \
        } } }
#define STORE_HALF(OT) { \
    _Pragma("unroll") \
    for (int wf = 0; wf < 2; ++wf) { \
        int w = wf * 32 + l31; \
        if (w < WO) { \
            _Pragma("unroll") \
            for (int reg = 0; reg < 16; ++reg) { \
                int o = (OT) * 32 + (reg & 3) + 8 * (reg >> 2) + 4 * g2; \
                out[((b * COUT + o) * HO + h) * WO + w] = acc[OT][wf][reg]; \
            } } } }

    __syncthreads();                       // all GEMM reads of phi done
    if (kh == 1) WR_FULL(0);
    if (kh == 3) WR_FULL(16384);
    __syncthreads();
    if (kh == 0) ADD_FULL(0);              // w0: sum of j 0..3
    if (kh == 2) ADD_FULL(16384);          // w2: sum of j 4..7
    __syncthreads();
    if (kh == 2) WR_HALF(0, 0);            // w2's o-low  -> for w0
    if (kh == 0) WR_HALF(1, 8192);         // w0's o-high -> for w2
    __syncthreads();
    if (kh == 0) { ADD_HALF(0, 0);    STORE_HALF(0); }   // w0 owns o 0..31
    if (kh == 2) { ADD_HALF(1, 8192); STORE_HALF(1); }   // w2 owns o 32..63
}

// ---- fallback (ws too small for bt): R2-proven kernel, coeff from f32 ----
__global__ __launch_bounds__(256, 4) void kan_conv_fb(
        const float* __restrict__ x, const float* __restrict__ coeff_f,
        float* __restrict__ out) {
    const int h    = blockIdx.x;
    const int b    = blockIdx.y;
    const int tid  = threadIdx.x;
    const int lane = tid & 63;
    const int wv   = tid >> 6;
    const int g    = lane >> 4;
    const int l15  = lane & 15;
    const int obase = (wv >> 1) << 5;
    const int wbase = (wv & 1) << 5;

    __shared__ __align__(16) ushort phi_lds[3 * JC * W_IN * NB];
    __shared__ uint lut[72];
    if (tid < 72) {
        int tap = tid;
        int j  = tap / 9;
        int r9 = tap - j * 9;
        int kt = r9 / 3;
        int lt = r9 - kt * 3;
        lut[tap] = (uint)(((kt * JC + j) * W_IN) * NB) | ((uint)lt << 16)
                 | ((uint)j << 20) | ((uint)r9 << 24);
    }
    v4f acc00 = {0.f, 0.f, 0.f, 0.f};
    v4f acc01 = acc00, acc10 = acc00, acc11 = acc00;
    const int aoff = obase + l15;
    float xv[6];
    #pragma unroll
    for (int it = 0; it < 6; ++it) {
        int n = it * 256 + tid;
        xv[it] = x[((b * CIN + ((n >> 6) & 7)) * H_IN + (h + (n >> 9))) * W_IN + (n & 63)];
    }
    for (int jc = 0; jc < NCH; ++jc) {
        #pragma unroll
        for (int it = 0; it < 6; ++it) {
            int n = it * 256 + tid;
            float s  = xv[it] * 11.0f;
            int i0 = (int)s;
            i0 = i0 < 0 ? 0 : (i0 > 10 ? 10 : i0);
            float u  = s - (float)i0;
            float um = 1.0f - u;
            float u2 = u * u, u3 = u2 * u;
            const float inv6 = 1.0f / 6.0f;
            float n0 = um * um * um * inv6;
            float n1 = (3.0f * u3 - 6.0f * u2 + 4.0f) * inv6;
            float n2 = (-3.0f * u3 + 3.0f * u2 + 3.0f * u + 1.0f) * inv6;
            float n3 = u3 * inv6;
            u64 V = (u64)f2bf(n0) | ((u64)f2bf(n1) << 16)
                  | ((u64)f2bf(n2) << 32) | ((u64)f2bf(n3) << 48);
            int bi = i0 - 3;
            u64 lo = bi < 0 ? (V >> (uint)(-16 * bi))
                   : bi < 4 ? (V << (uint)(16 * bi)) : 0ull;
            u64 hi = bi <= 0 ? 0ull
                   : bi < 4 ? (V >> (uint)(64 - 16 * bi))
                   : (V << (uint)(16 * bi - 64));
            v2u64 pk; pk[0] = lo; pk[1] = hi;
            *reinterpret_cast<v2u64*>(&phi_lds[n << 3]) = pk;
        }
        if (jc + 1 < NCH) {
            int j0n = (jc + 1) * JC;
            #pragma unroll
            for (int it = 0; it < 6; ++it) {
                int n = it * 256 + tid;
                xv[it] = x[((b * CIN + j0n + ((n >> 6) & 7)) * H_IN + (h + (n >> 9))) * W_IN + (n & 63)];
            }
        }
        __syncthreads();
        const int j0 = jc * JC;
        #pragma unroll 6
        for (int kk = 0; kk < 18; ++kk) {
            int tap = (kk << 2) + g;
            uint e = lut[tap];
            int philoc = (int)(e & 0xffffu);
            int lt     = (int)((e >> 16) & 3u);
            int w0 = wbase + l15 + lt;
            int w1 = w0 + 16;
            w0 = w0 < 63 ? w0 : 63;
            w1 = w1 < 63 ? w1 : 63;
            v8s pb0 = *reinterpret_cast<const v8s*>(&phi_lds[philoc + (w0 << 3)]);
            v8s pb1 = *reinterpret_cast<const v8s*>(&phi_lds[philoc + (w1 << 3)]);
            int j  = (int)((e >> 20) & 15u);
            int r9 = (int)((e >> 24) & 15u);
            const float* cf = coeff_f + (((aoff * CIN + (j0 + j)) * 9 + r9) << 3);
            v8s pa0, pa1;
            #pragma unroll
            for (int z = 0; z < 8; ++z) pa0[z] = (short)f2bf(cf[z]);
            const float* cf2 = cf + (CIN * 9 * NB * 16);
            #pragma unroll
            for (int z = 0; z < 8; ++z) pa1[z] = (short)f2bf(cf2[z]);
            acc00 = MFMA16(pa0, pb0, acc00);
            acc01 = MFMA16(pa0, pb1, acc01);
            acc10 = MFMA16(pa1, pb0, acc10);
            acc11 = MFMA16(pa1, pb1, acc11);
        }
        __syncthreads();
    }
    const int wc0 = wbase + l15;
    const int wc1 = wc0 + 16;
    #pragma unroll
    for (int i = 0; i < 2; ++i) {
        v4f a0 = (i == 0) ? acc00 : acc10;
        v4f a1 = (i == 0) ? acc01 : acc11;
        int o = obase + i * 16 + (g << 2);
        #pragma unroll
        for (int r = 0; r < 4; ++r) {
            int off = ((b * COUT + o + r) * HO + h) * WO;
            if (wc0 < WO) out[off + wc0] = a0[r];
            if (wc1 < WO) out[off + wc1] = a1[r];
        }
    }
}

extern "C" void kernel_launch(void* const* d_in, const int* in_sizes, int n_in,
                              void* d_out, int out_size, void* d_ws, size_t ws_size,
                              hipStream_t stream) {
    const float* x     = (const float*)d_in[0];
    const float* coeff = (const float*)d_in[1];
    float* out = (float*)d_out;

    const size_t bt_bytes = (size_t)294912 * 2;  // 576 KB
    if (ws_size >= bt_bytes) {
        ushort* bt = (ushort*)d_ws;
        prep_coeff_kernel<<<(294912 + 255) / 256, 256, 0, stream>>>(coeff, bt);
        kan_conv_pf<<<HO * B_N, 256, 0, stream>>>(x, bt, out);
    } else {
        kan_conv_fb<<<dim3(HO, B_N), 256, 0, stream>>>(x, coeff, out);
    }
}